// Round 1
// baseline (907.482 us; speedup 1.0000x reference)
//
#include <hip/hip_runtime.h>
#include <cstdint>
#include <cstddef>

#define AS1 __attribute__((address_space(1)))
#define AS3 __attribute__((address_space(3)))

typedef __bf16 bf16x8 __attribute__((ext_vector_type(8)));
typedef __bf16 bf16x4 __attribute__((ext_vector_type(4)));
typedef float  f32x4  __attribute__((ext_vector_type(4)));

namespace {

constexpr int NB = 4;      // batch
constexpr int S  = 1024;   // sequence length
constexpr int D  = 1024;   // model dim
constexpr int NH = 16;     // heads
constexpr int DP = 64;     // head dim

// ---------------- f32 -> bf16 hi/lo split (elementwise, float4-vectorized) ----------------
__global__ void __launch_bounds__(256) split_k(const float* __restrict__ src,
                                               __bf16* __restrict__ hi,
                                               __bf16* __restrict__ lo,
                                               size_t n4) {
  size_t i = (size_t)blockIdx.x * blockDim.x + threadIdx.x;
  const size_t stride = (size_t)gridDim.x * blockDim.x;
  for (; i < n4; i += stride) {
    const float4 v = ((const float4*)src)[i];
    bf16x4 h;
    h[0] = (__bf16)v.x; h[1] = (__bf16)v.y; h[2] = (__bf16)v.z; h[3] = (__bf16)v.w;
    ((bf16x4*)hi)[i] = h;
    if (lo != nullptr) {
      bf16x4 l;
      l[0] = (__bf16)(v.x - (float)h[0]);
      l[1] = (__bf16)(v.y - (float)h[1]);
      l[2] = (__bf16)(v.z - (float)h[2]);
      l[3] = (__bf16)(v.w - (float)h[3]);
      ((bf16x4*)lo)[i] = l;
    }
  }
}

// ------------- batched transpose+split: src [Z][R][C] f32 -> dst [Z][C][R] bf16 hi/lo -------------
__global__ void __launch_bounds__(256) tsplit_k(const float* __restrict__ src,
                                                __bf16* __restrict__ hi,
                                                __bf16* __restrict__ lo,
                                                int R, int C) {
  __shared__ float tile[32][33];   // +1 pad: conflict-free column reads
  const int z = blockIdx.z;
  const float* sp = src + (size_t)z * R * C;
  __bf16* hp = hi + (size_t)z * R * C;
  __bf16* lp = lo + (size_t)z * R * C;
  const int r0 = blockIdx.y * 32, c0 = blockIdx.x * 32;
  const int tx = threadIdx.x, ty = threadIdx.y;   // block (32,8)
  #pragma unroll
  for (int rr = ty; rr < 32; rr += 8)
    tile[rr][tx] = sp[(size_t)(r0 + rr) * C + c0 + tx];
  __syncthreads();
  #pragma unroll
  for (int cc = ty; cc < 32; cc += 8) {
    const float v = tile[tx][cc];               // = src[r0+tx][c0+cc]
    const __bf16 h = (__bf16)v;
    const size_t o = (size_t)(c0 + cc) * R + r0 + tx;
    hp[o] = h;
    lp[o] = (__bf16)(v - (float)h);
  }
}

// ---------------- in-place row softmax, rows of 1024 (one block per row) ----------------
__global__ void __launch_bounds__(256) softmax_k(float* __restrict__ aw) {
  const size_t row = blockIdx.x;
  float* p = aw + row * 1024;
  const int tid = threadIdx.x;
  float4 v = ((const float4*)p)[tid];
  float m = fmaxf(fmaxf(v.x, v.y), fmaxf(v.z, v.w));
  #pragma unroll
  for (int off = 32; off > 0; off >>= 1) m = fmaxf(m, __shfl_xor(m, off));
  __shared__ float red[8];
  const int wv = tid >> 6, ln = tid & 63;
  if (ln == 0) red[wv] = m;
  __syncthreads();
  m = fmaxf(fmaxf(red[0], red[1]), fmaxf(red[2], red[3]));
  const float e0 = __expf(v.x - m), e1 = __expf(v.y - m);
  const float e2 = __expf(v.z - m), e3 = __expf(v.w - m);
  float s = (e0 + e1) + (e2 + e3);
  #pragma unroll
  for (int off = 32; off > 0; off >>= 1) s += __shfl_xor(s, off);
  if (ln == 0) red[4 + wv] = s;
  __syncthreads();
  s = (red[4] + red[5]) + (red[6] + red[7]);
  const float inv = 1.0f / s;
  float4 o; o.x = e0 * inv; o.y = e1 * inv; o.z = e2 * inv; o.w = e3 * inv;
  ((float4*)p)[tid] = o;
}

// ---------------- generic split-bf16 MFMA GEMM ----------------
// C[m][n] = sum_k A[m][k] * Bt[n][k]   (Bt = B pre-transposed, bf16 hi/lo)
// Split passes: Ah*Bh (+ Ah*Bl if B_LO) (+ Al*Bh if A_LO).
// A_F32: A is f32 in global; staged to LDS as bf16-hi only (used for AW in the AV GEMM).
// EPI: 0 = plain store, 1 = +bias[col], 2 = scores (val/8 - 1e5*mask[row*N+col]).
// z decomposition: z = zb*ZH + zh; per-operand strides (sXb, sXh) give the slice base.
struct GemmArgs {
  const void*   Ah; const void* Al;
  const __bf16* Bh; const __bf16* Bl;
  float* C; const float* bias; const int* mask;
  int M, N, K, ZH;
  long long lda, ldb, ldc;
  long long sAb, sAh, sBb, sBh, sCb, sCh, sMb;
};

template<int BM, int BN, int WM, int WN, bool A_LO, bool B_LO, bool A_F32, int EPI>
__global__ void __launch_bounds__(WM * WN * 64) gemm_k(GemmArgs g) {
  constexpr int NW = WM * WN, NT = NW * 64, BK = 32;
  constexpr int WMsz = BM / WM, WNsz = BN / WN;
  constexpr int FM = WMsz / 16, FN = WNsz / 16;
  static_assert((BM * BK / 8) % NT == 0 && (BN * BK / 8) % NT == 0, "stage divisibility");

  __shared__ __attribute__((aligned(16))) __bf16 Ash[BM * BK];
  __shared__ __attribute__((aligned(16))) __bf16 Asl[A_LO ? BM * BK : 8];
  __shared__ __attribute__((aligned(16))) __bf16 Bsh[BN * BK];
  __shared__ __attribute__((aligned(16))) __bf16 Bsl[B_LO ? BN * BK : 8];

  const int tid = threadIdx.x, wave = tid >> 6, lane = tid & 63;
  const int z = blockIdx.z;
  const int zb = z / g.ZH, zh = z - zb * g.ZH;

  const float*  Af = A_F32 ? (const float*)g.Ah + (size_t)zb * g.sAb + (size_t)zh * g.sAh : nullptr;
  const __bf16* Ah = !A_F32 ? (const __bf16*)g.Ah + (size_t)zb * g.sAb + (size_t)zh * g.sAh : nullptr;
  const __bf16* Al = A_LO  ? (const __bf16*)g.Al + (size_t)zb * g.sAb + (size_t)zh * g.sAh : nullptr;
  const __bf16* Bh = g.Bh + (size_t)zb * g.sBb + (size_t)zh * g.sBh;
  const __bf16* Bl = B_LO ? g.Bl + (size_t)zb * g.sBb + (size_t)zh * g.sBh : nullptr;
  float* C = g.C + (size_t)zb * g.sCb + (size_t)zh * g.sCh;
  const int* mk = (EPI == 2) ? g.mask + (size_t)zb * g.sMb : nullptr;

  const int m0 = blockIdx.y * BM, n0 = blockIdx.x * BN;
  const int wm = wave / WN, wn = wave % WN;
  const int lc = lane & 15;            // A row / B col / C col within 16x16 frag
  const int lkb = (lane >> 4) * 8;     // k base for A/B fragments (contiguous 8)
  const int lr4 = (lane >> 4) * 4;     // C row group base

  f32x4 acc[FM][FN] = {};

  for (int k0 = 0; k0 < g.K; k0 += BK) {
    // ---- stage A tile [BM][BK] ----
    if constexpr (A_F32) {
      constexpr int ITF = (BM * BK / 4) / NT;
      #pragma unroll
      for (int i = 0; i < ITF; ++i) {
        const int f = i * NT + tid;
        const int row = f >> 3, c4 = f & 7;
        const float4 v = *(const float4*)(Af + (size_t)(m0 + row) * g.lda + k0 + c4 * 4);
        bf16x4 h;
        h[0] = (__bf16)v.x; h[1] = (__bf16)v.y; h[2] = (__bf16)v.z; h[3] = (__bf16)v.w;
        *(bf16x4*)&Ash[row * BK + c4 * 4] = h;
      }
    } else {
      constexpr int ITA = (BM * BK / 8) / NT;
      #pragma unroll
      for (int i = 0; i < ITA; ++i) {
        const int cb = (i * NW + wave) * 64;            // wave-uniform chunk base
        const int ch = cb + lane;
        const int row = ch >> 2, c8 = ch & 3;           // 4 chunks of 8 bf16 per row
        const size_t go = (size_t)(m0 + row) * g.lda + k0 + c8 * 8;
        __builtin_amdgcn_global_load_lds((AS1 void*)(Ah + go),
                                         (AS3 void*)(&Ash[cb * 8]), 16, 0, 0);
        if constexpr (A_LO)
          __builtin_amdgcn_global_load_lds((AS1 void*)(Al + go),
                                           (AS3 void*)(&Asl[cb * 8]), 16, 0, 0);
      }
    }
    // ---- stage B tile [BN][BK] ----
    {
      constexpr int ITB = (BN * BK / 8) / NT;
      #pragma unroll
      for (int i = 0; i < ITB; ++i) {
        const int cb = (i * NW + wave) * 64;
        const int ch = cb + lane;
        const int row = ch >> 2, c8 = ch & 3;
        const size_t go = (size_t)(n0 + row) * g.ldb + k0 + c8 * 8;
        __builtin_amdgcn_global_load_lds((AS1 void*)(Bh + go),
                                         (AS3 void*)(&Bsh[cb * 8]), 16, 0, 0);
        if constexpr (B_LO)
          __builtin_amdgcn_global_load_lds((AS1 void*)(Bl + go),
                                           (AS3 void*)(&Bsl[cb * 8]), 16, 0, 0);
      }
    }
    __syncthreads();

    bf16x8 ah[FM], al[FM], bh[FN], bl[FN];
    #pragma unroll
    for (int i = 0; i < FM; ++i) {
      const int r = wm * WMsz + i * 16 + lc;
      ah[i] = *(const bf16x8*)&Ash[r * BK + lkb];
      if constexpr (A_LO) al[i] = *(const bf16x8*)&Asl[r * BK + lkb];
    }
    #pragma unroll
    for (int j = 0; j < FN; ++j) {
      const int r = wn * WNsz + j * 16 + lc;
      bh[j] = *(const bf16x8*)&Bsh[r * BK + lkb];
      if constexpr (B_LO) bl[j] = *(const bf16x8*)&Bsl[r * BK + lkb];
    }
    #pragma unroll
    for (int i = 0; i < FM; ++i)
      #pragma unroll
      for (int j = 0; j < FN; ++j) {
        acc[i][j] = __builtin_amdgcn_mfma_f32_16x16x32_bf16(ah[i], bh[j], acc[i][j], 0, 0, 0);
        if constexpr (B_LO)
          acc[i][j] = __builtin_amdgcn_mfma_f32_16x16x32_bf16(ah[i], bl[j], acc[i][j], 0, 0, 0);
        if constexpr (A_LO)
          acc[i][j] = __builtin_amdgcn_mfma_f32_16x16x32_bf16(al[i], bh[j], acc[i][j], 0, 0, 0);
      }
    __syncthreads();
  }

  // ---- epilogue: C/D frag mapping col=lane&15, row=(lane>>4)*4+r (m89-verified) ----
  #pragma unroll
  for (int i = 0; i < FM; ++i)
    #pragma unroll
    for (int j = 0; j < FN; ++j)
      #pragma unroll
      for (int r = 0; r < 4; ++r) {
        const int row = m0 + wm * WMsz + i * 16 + lr4 + r;
        const int col = n0 + wn * WNsz + j * 16 + lc;
        float val = acc[i][j][r];
        if constexpr (EPI == 1) val += g.bias[col];
        if constexpr (EPI == 2) val = val * 0.125f - 100000.0f * (float)mk[(size_t)row * g.N + col];
        C[(size_t)row * g.ldc + col] = val;
      }
}

} // namespace

extern "C" void kernel_launch(void* const* d_in, const int* in_sizes, int n_in,
                              void* d_out, int out_size, void* d_ws, size_t ws_size,
                              hipStream_t stream) {
  (void)in_sizes; (void)n_in; (void)out_size; (void)ws_size;

  const float* v_in = (const float*)d_in[0];
  const float* q_in = (const float*)d_in[1];
  const float* k_in = (const float*)d_in[2];
  const int*   mask = (const int*)d_in[3];
  const float* Gm   = (const float*)d_in[4];
  const float* wq = (const float*)d_in[5];  const float* bq = (const float*)d_in[6];
  const float* wk = (const float*)d_in[7];  const float* bk = (const float*)d_in[8];
  const float* wv = (const float*)d_in[9];  const float* bv = (const float*)d_in[10];
  const float* wo = (const float*)d_in[11]; const float* bo = (const float*)d_in[12];

  float* out = (float*)d_out;                       // [B,S,D]
  float* aw  = out + (size_t)NB * S * D;            // [B,H,S,S] scores -> softmax in place

  // Workspace arena (130 MB, phase-aliased; offsets in MiB):
  //  0..48  : q/k/v hi+lo (phase1)          -> Qp hi/lo, KpT hi/lo, VpT hi/lo (phase2)
  //  48..64 : wqT,wkT,wvT,woT hi/lo
  //  64..80 : Qp f32                        -> Khat hi/lo (phase3)
  //  80..96 : Kp f32                        -> Khat f32 (phase3)
  //  96..112: Vp f32                        -> attn f32 (phase3)
  //  112..114: G bf16 (exact)
  //  114..130: attn hi/lo
  char* ws = (char*)d_ws;
  auto BF = [&](size_t mb) { return (__bf16*)(ws + (mb << 20)); };
  auto FP = [&](size_t mb) { return (float*)(ws + (mb << 20)); };

  const size_t BSD = (size_t)NB * S * D;
  const dim3 tb(32, 8);

  // --- input prep ---
  split_k<<<2048, 256, 0, stream>>>(q_in, BF(0),  BF(8),  BSD / 4);
  split_k<<<2048, 256, 0, stream>>>(k_in, BF(16), BF(24), BSD / 4);
  split_k<<<2048, 256, 0, stream>>>(v_in, BF(32), BF(40), BSD / 4);
  split_k<<<1024, 256, 0, stream>>>(Gm, BF(112), nullptr, (size_t)S * S / 4);  // G is 0/1: exact in bf16
  tsplit_k<<<dim3(32, 32, 1), tb, 0, stream>>>(wq, BF(48), BF(50), D, D);
  tsplit_k<<<dim3(32, 32, 1), tb, 0, stream>>>(wk, BF(52), BF(54), D, D);
  tsplit_k<<<dim3(32, 32, 1), tb, 0, stream>>>(wv, BF(56), BF(58), D, D);
  tsplit_k<<<dim3(32, 32, 1), tb, 0, stream>>>(wo, BF(60), BF(62), D, D);

  // --- projections: [4096,1024] @ W + b ---
  GemmArgs pa{};
  pa.M = NB * S; pa.N = D; pa.K = D; pa.ZH = 1;
  pa.lda = D; pa.ldb = D; pa.ldc = D;
  pa.Ah = BF(0);  pa.Al = BF(8);  pa.Bh = BF(48); pa.Bl = BF(50); pa.C = FP(64); pa.bias = bq;
  gemm_k<128, 128, 2, 2, true, true, false, 1><<<dim3(8, 32, 1), 256, 0, stream>>>(pa);
  pa.Ah = BF(16); pa.Al = BF(24); pa.Bh = BF(52); pa.Bl = BF(54); pa.C = FP(80); pa.bias = bk;
  gemm_k<128, 128, 2, 2, true, true, false, 1><<<dim3(8, 32, 1), 256, 0, stream>>>(pa);
  pa.Ah = BF(32); pa.Al = BF(40); pa.Bh = BF(56); pa.Bl = BF(58); pa.C = FP(96); pa.bias = bv;
  gemm_k<128, 128, 2, 2, true, true, false, 1><<<dim3(8, 32, 1), 256, 0, stream>>>(pa);

  // --- re-layout projected tensors ---
  split_k<<<2048, 256, 0, stream>>>(FP(64), BF(0), BF(8), BSD / 4);                 // Qp -> hi/lo
  tsplit_k<<<dim3(32, 32, NB), tb, 0, stream>>>(FP(80), BF(16), BF(24), S, D);      // Kp -> KpT
  tsplit_k<<<dim3(32, 32, NB), tb, 0, stream>>>(FP(96), BF(32), BF(40), S, D);      // Vp -> VpT

  // --- Khat[b] = G @ Kp[b]  (G symmetric => no transpose; A-lo pass skipped, G exact) ---
  GemmArgs ka{};
  ka.M = S; ka.N = D; ka.K = S; ka.ZH = 1;
  ka.lda = S; ka.ldb = S; ka.ldc = D;
  ka.sBb = (long long)D * S; ka.sCb = (long long)S * D;
  ka.Ah = BF(112); ka.Bh = BF(16); ka.Bl = BF(24); ka.C = FP(80);
  gemm_k<128, 128, 2, 2, false, true, false, 0><<<dim3(8, 8, NB), 256, 0, stream>>>(ka);
  split_k<<<2048, 256, 0, stream>>>(FP(80), BF(64), BF(72), BSD / 4);               // Khat -> hi/lo

  // --- scores[b,h] = Qh . Khat_h^T / 8 - 1e5*mask  ->  aw (raw scores) ---
  GemmArgs sa{};
  sa.M = S; sa.N = S; sa.K = DP; sa.ZH = NH;
  sa.lda = D; sa.ldb = D; sa.ldc = S;
  sa.sAb = (long long)S * D; sa.sAh = DP;
  sa.sBb = (long long)S * D; sa.sBh = DP;
  sa.sCb = (long long)NH * S * S; sa.sCh = (long long)S * S;
  sa.sMb = (long long)S * S;
  sa.Ah = BF(0); sa.Al = BF(8); sa.Bh = BF(64); sa.Bl = BF(72); sa.C = aw; sa.mask = mask;
  gemm_k<128, 128, 2, 2, true, true, false, 2><<<dim3(8, 8, NB * NH), 256, 0, stream>>>(sa);

  // --- softmax rows in place (this IS output #1) ---
  softmax_k<<<NB * NH * S, 256, 0, stream>>>(aw);

  // --- attn[b,:,h*64:...] = AW[b,h] @ Vh  (AW f32 staged to bf16-hi in kernel) ---
  GemmArgs va{};
  va.M = S; va.N = DP; va.K = S; va.ZH = NH;
  va.lda = S; va.ldb = S; va.ldc = D;
  va.sAb = (long long)NH * S * S; va.sAh = (long long)S * S;
  va.sBb = (long long)D * S;      va.sBh = (long long)DP * S;
  va.sCb = (long long)S * D;      va.sCh = DP;
  va.Ah = aw; va.Bh = BF(32); va.Bl = BF(40); va.C = FP(96);
  gemm_k<128, 64, 2, 2, false, true, true, 0><<<dim3(1, 8, NB * NH), 256, 0, stream>>>(va);

  // --- output = attn @ wo + bo ---
  split_k<<<2048, 256, 0, stream>>>(FP(96), BF(114), BF(122), BSD / 4);
  GemmArgs fa{};
  fa.M = NB * S; fa.N = D; fa.K = D; fa.ZH = 1;
  fa.lda = D; fa.ldb = D; fa.ldc = D;
  fa.Ah = BF(114); fa.Al = BF(122); fa.Bh = BF(60); fa.Bl = BF(62); fa.C = out; fa.bias = bo;
  gemm_k<128, 128, 2, 2, true, true, false, 1><<<dim3(8, 32, 1), 256, 0, stream>>>(fa);
}

// Round 2
// 865.690 us; speedup vs baseline: 1.0483x; 1.0483x over previous
//
#include <hip/hip_runtime.h>
#include <cstdint>
#include <cstddef>

#define AS1 __attribute__((address_space(1)))
#define AS3 __attribute__((address_space(3)))

typedef __bf16 bf16x8 __attribute__((ext_vector_type(8)));
typedef __bf16 bf16x4 __attribute__((ext_vector_type(4)));
typedef float  f32x4  __attribute__((ext_vector_type(4)));

namespace {

constexpr int NB = 4;      // batch
constexpr int S  = 1024;   // sequence length
constexpr int D  = 1024;   // model dim
constexpr int NH = 16;     // heads
constexpr int DP = 64;     // head dim

// ---------------- f32 -> bf16 hi (optionally +lo) split, float4-vectorized ----------------
__global__ void __launch_bounds__(256) split_k(const float* __restrict__ src,
                                               __bf16* __restrict__ hi,
                                               __bf16* __restrict__ lo,
                                               size_t n4) {
  size_t i = (size_t)blockIdx.x * blockDim.x + threadIdx.x;
  const size_t stride = (size_t)gridDim.x * blockDim.x;
  for (; i < n4; i += stride) {
    const float4 v = ((const float4*)src)[i];
    bf16x4 h;
    h[0] = (__bf16)v.x; h[1] = (__bf16)v.y; h[2] = (__bf16)v.z; h[3] = (__bf16)v.w;
    ((bf16x4*)hi)[i] = h;
    if (lo != nullptr) {
      bf16x4 l;
      l[0] = (__bf16)(v.x - (float)h[0]);
      l[1] = (__bf16)(v.y - (float)h[1]);
      l[2] = (__bf16)(v.z - (float)h[2]);
      l[3] = (__bf16)(v.w - (float)h[3]);
      ((bf16x4*)lo)[i] = l;
    }
  }
}

// ------------- batched q/k/v hi/lo split: z selects tensor; dst stride fixed -------------
__global__ void __launch_bounds__(256) split3_k(const float* __restrict__ s0,
                                                const float* __restrict__ s1,
                                                const float* __restrict__ s2,
                                                __bf16* __restrict__ hi0, size_t n4) {
  const float* srcs[3] = {s0, s1, s2};
  const float* src = srcs[blockIdx.z];
  __bf16* hi = hi0 + (size_t)blockIdx.z * 8388608;   // 16 MiB stride (hi+lo pair)
  __bf16* lo = hi + 4194304;                         // +8 MiB
  size_t i = (size_t)blockIdx.x * blockDim.x + threadIdx.x;
  const size_t stride = (size_t)gridDim.x * blockDim.x;
  for (; i < n4; i += stride) {
    const float4 v = ((const float4*)src)[i];
    bf16x4 h, l;
    h[0] = (__bf16)v.x; h[1] = (__bf16)v.y; h[2] = (__bf16)v.z; h[3] = (__bf16)v.w;
    l[0] = (__bf16)(v.x - (float)h[0]);
    l[1] = (__bf16)(v.y - (float)h[1]);
    l[2] = (__bf16)(v.z - (float)h[2]);
    l[3] = (__bf16)(v.w - (float)h[3]);
    ((bf16x4*)hi)[i] = h;
    ((bf16x4*)lo)[i] = l;
  }
}

// ------------- batched weight transpose+split: z selects {wq,wk,wv,wo}; 1024x1024 each -------------
__global__ void __launch_bounds__(256) tsplit4_k(const float* __restrict__ s0,
                                                 const float* __restrict__ s1,
                                                 const float* __restrict__ s2,
                                                 const float* __restrict__ s3,
                                                 __bf16* __restrict__ hi0) {
  __shared__ float tile[32][33];
  const float* srcs[4] = {s0, s1, s2, s3};
  const float* sp = srcs[blockIdx.z];
  __bf16* hp = hi0 + (size_t)blockIdx.z * 2097152;   // 4 MiB stride (hi+lo pair)
  __bf16* lp = hp + 1048576;                         // +2 MiB
  const int r0 = blockIdx.y * 32, c0 = blockIdx.x * 32;
  const int tx = threadIdx.x, ty = threadIdx.y;      // block (32,8)
  #pragma unroll
  for (int rr = ty; rr < 32; rr += 8)
    tile[rr][tx] = sp[(size_t)(r0 + rr) * D + c0 + tx];
  __syncthreads();
  #pragma unroll
  for (int cc = ty; cc < 32; cc += 8) {
    const float v = tile[tx][cc];                    // = src[r0+tx][c0+cc]
    const __bf16 h = (__bf16)v;
    const size_t o = (size_t)(c0 + cc) * D + r0 + tx;
    hp[o] = h;
    lp[o] = (__bf16)(v - (float)h);
  }
}

// ---------------- in-place row softmax + bf16-hi copy, rows of 1024 ----------------
__global__ void __launch_bounds__(256) softmax_k(float* __restrict__ aw,
                                                 __bf16* __restrict__ awh) {
  const size_t row = blockIdx.x;
  float* p = aw + row * 1024;
  const int tid = threadIdx.x;
  float4 v = ((const float4*)p)[tid];
  float m = fmaxf(fmaxf(v.x, v.y), fmaxf(v.z, v.w));
  #pragma unroll
  for (int off = 32; off > 0; off >>= 1) m = fmaxf(m, __shfl_xor(m, off));
  __shared__ float red[8];
  const int wv = tid >> 6, ln = tid & 63;
  if (ln == 0) red[wv] = m;
  __syncthreads();
  m = fmaxf(fmaxf(red[0], red[1]), fmaxf(red[2], red[3]));
  const float e0 = __expf(v.x - m), e1 = __expf(v.y - m);
  const float e2 = __expf(v.z - m), e3 = __expf(v.w - m);
  float s = (e0 + e1) + (e2 + e3);
  #pragma unroll
  for (int off = 32; off > 0; off >>= 1) s += __shfl_xor(s, off);
  if (ln == 0) red[4 + wv] = s;
  __syncthreads();
  s = (red[4] + red[5]) + (red[6] + red[7]);
  const float inv = 1.0f / s;
  float4 o; o.x = e0 * inv; o.y = e1 * inv; o.z = e2 * inv; o.w = e3 * inv;
  ((float4*)p)[tid] = o;
  bf16x4 hb;
  hb[0] = (__bf16)o.x; hb[1] = (__bf16)o.y; hb[2] = (__bf16)o.z; hb[3] = (__bf16)o.w;
  ((bf16x4*)(awh + row * 1024))[tid] = hb;
}

// ---------------- generic split-bf16 MFMA GEMM ----------------
// C[m][n] = sum_k A[m][k] * Bt[n][k]   (Bt = B pre-transposed, bf16 hi/lo)
// Split passes: Ah*Bh (+ Ah*Bl if B_LO) (+ Al*Bh if A_LO).
// EPI: 0 = f32 store (+bias if non-null)
//      2 = scores: val/8 - 1e5*mask[row*N+col], f32 store
//      3 = split store: bf16 hi/lo, same layout (+bias if non-null)
//      4 = transposed split store per batch of 1024 rows: dst[b][col][row&1023]
struct GemmArgs {
  const __bf16 *Ah, *Al, *Bh, *Bl;
  float* C; __bf16* Chi; __bf16* Clo;
  const float* bias; const int* mask;
  int N, K, ZH;
  long long lda, ldb, ldc;
  long long sAb, sAh, sBb, sBh, sCb, sCh, sMb;
};

template<int BM, int BN, int WM, int WN, bool A_LO, bool B_LO, int EPI>
__global__ void __launch_bounds__(WM * WN * 64) gemm_k(GemmArgs g) {
  constexpr int NW = WM * WN, NT = NW * 64, BK = 32;
  constexpr int WMsz = BM / WM, WNsz = BN / WN;
  constexpr int FM = WMsz / 16, FN = WNsz / 16;
  static_assert((BM * BK / 8) % NT == 0 && (BN * BK / 8) % NT == 0, "stage divisibility");

  __shared__ __attribute__((aligned(16))) __bf16 Ash[BM * BK];
  __shared__ __attribute__((aligned(16))) __bf16 Asl[A_LO ? BM * BK : 8];
  __shared__ __attribute__((aligned(16))) __bf16 Bsh[BN * BK];
  __shared__ __attribute__((aligned(16))) __bf16 Bsl[B_LO ? BN * BK : 8];

  const int tid = threadIdx.x, wave = tid >> 6, lane = tid & 63;
  const int z = blockIdx.z;
  const int zb = z / g.ZH, zh = z - zb * g.ZH;

  const __bf16* Ah = g.Ah + (size_t)zb * g.sAb + (size_t)zh * g.sAh;
  const __bf16* Al = A_LO ? g.Al + (size_t)zb * g.sAb + (size_t)zh * g.sAh : nullptr;
  const __bf16* Bh = g.Bh + (size_t)zb * g.sBb + (size_t)zh * g.sBh;
  const __bf16* Bl = B_LO ? g.Bl + (size_t)zb * g.sBb + (size_t)zh * g.sBh : nullptr;
  float* C = (EPI == 0 || EPI == 2) ? g.C + (size_t)zb * g.sCb + (size_t)zh * g.sCh : nullptr;
  __bf16* Chi = (EPI == 3) ? g.Chi + (size_t)zb * g.sCb + (size_t)zh * g.sCh
                           : g.Chi;   // EPI 4: batch offset handled per-row
  __bf16* Clo = (EPI == 3) ? g.Clo + (size_t)zb * g.sCb + (size_t)zh * g.sCh
                           : g.Clo;
  const int* mk = (EPI == 2) ? g.mask + (size_t)zb * g.sMb : nullptr;

  const int m0 = blockIdx.y * BM, n0 = blockIdx.x * BN;
  const int wm = wave / WN, wn = wave % WN;
  const int lc = lane & 15;            // A row / B col / C col within 16x16 frag
  const int lkb = (lane >> 4) * 8;     // k base for A/B fragments (contiguous 8)
  const int lr4 = (lane >> 4) * 4;     // C row group base

  f32x4 acc[FM][FN] = {};

  for (int k0 = 0; k0 < g.K; k0 += BK) {
    // ---- stage A tile [BM][BK] ----
    {
      constexpr int ITA = (BM * BK / 8) / NT;
      #pragma unroll
      for (int i = 0; i < ITA; ++i) {
        const int cb = (i * NW + wave) * 64;            // wave-uniform chunk base
        const int ch = cb + lane;
        const int row = ch >> 2, c8 = ch & 3;           // 4 chunks of 8 bf16 per row
        const size_t go = (size_t)(m0 + row) * g.lda + k0 + c8 * 8;
        __builtin_amdgcn_global_load_lds((AS1 void*)(Ah + go),
                                         (AS3 void*)(&Ash[cb * 8]), 16, 0, 0);
        if constexpr (A_LO)
          __builtin_amdgcn_global_load_lds((AS1 void*)(Al + go),
                                           (AS3 void*)(&Asl[cb * 8]), 16, 0, 0);
      }
    }
    // ---- stage B tile [BN][BK] ----
    {
      constexpr int ITB = (BN * BK / 8) / NT;
      #pragma unroll
      for (int i = 0; i < ITB; ++i) {
        const int cb = (i * NW + wave) * 64;
        const int ch = cb + lane;
        const int row = ch >> 2, c8 = ch & 3;
        const size_t go = (size_t)(n0 + row) * g.ldb + k0 + c8 * 8;
        __builtin_amdgcn_global_load_lds((AS1 void*)(Bh + go),
                                         (AS3 void*)(&Bsh[cb * 8]), 16, 0, 0);
        if constexpr (B_LO)
          __builtin_amdgcn_global_load_lds((AS1 void*)(Bl + go),
                                           (AS3 void*)(&Bsl[cb * 8]), 16, 0, 0);
      }
    }
    __syncthreads();

    bf16x8 ah[FM], al[FM], bh[FN], bl[FN];
    #pragma unroll
    for (int i = 0; i < FM; ++i) {
      const int r = wm * WMsz + i * 16 + lc;
      ah[i] = *(const bf16x8*)&Ash[r * BK + lkb];
      if constexpr (A_LO) al[i] = *(const bf16x8*)&Asl[r * BK + lkb];
    }
    #pragma unroll
    for (int j = 0; j < FN; ++j) {
      const int r = wn * WNsz + j * 16 + lc;
      bh[j] = *(const bf16x8*)&Bsh[r * BK + lkb];
      if constexpr (B_LO) bl[j] = *(const bf16x8*)&Bsl[r * BK + lkb];
    }
    #pragma unroll
    for (int i = 0; i < FM; ++i)
      #pragma unroll
      for (int j = 0; j < FN; ++j) {
        acc[i][j] = __builtin_amdgcn_mfma_f32_16x16x32_bf16(ah[i], bh[j], acc[i][j], 0, 0, 0);
        if constexpr (B_LO)
          acc[i][j] = __builtin_amdgcn_mfma_f32_16x16x32_bf16(ah[i], bl[j], acc[i][j], 0, 0, 0);
        if constexpr (A_LO)
          acc[i][j] = __builtin_amdgcn_mfma_f32_16x16x32_bf16(al[i], bh[j], acc[i][j], 0, 0, 0);
      }
    __syncthreads();
  }

  // ---- epilogue: C/D frag mapping col=lane&15, row=(lane>>4)*4+r (m89-verified) ----
  #pragma unroll
  for (int i = 0; i < FM; ++i)
    #pragma unroll
    for (int j = 0; j < FN; ++j) {
      const int row = m0 + wm * WMsz + i * 16 + lr4;
      const int col = n0 + wn * WNsz + j * 16 + lc;
      float v[4];
      #pragma unroll
      for (int r = 0; r < 4; ++r) v[r] = acc[i][j][r];
      if constexpr (EPI != 2) {
        if (g.bias != nullptr) {
          const float b = g.bias[col];
          #pragma unroll
          for (int r = 0; r < 4; ++r) v[r] += b;
        }
      }
      if constexpr (EPI == 0) {
        #pragma unroll
        for (int r = 0; r < 4; ++r)
          C[(size_t)(row + r) * g.ldc + col] = v[r];
      }
      if constexpr (EPI == 2) {
        #pragma unroll
        for (int r = 0; r < 4; ++r)
          C[(size_t)(row + r) * g.ldc + col] =
              v[r] * 0.125f - 100000.0f * (float)mk[(size_t)(row + r) * g.N + col];
      }
      if constexpr (EPI == 3) {
        #pragma unroll
        for (int r = 0; r < 4; ++r) {
          const __bf16 h = (__bf16)v[r];
          const size_t o = (size_t)(row + r) * g.ldc + col;
          Chi[o] = h;
          Clo[o] = (__bf16)(v[r] - (float)h);
        }
      }
      if constexpr (EPI == 4) {
        bf16x4 h4, l4;
        #pragma unroll
        for (int r = 0; r < 4; ++r) {
          h4[r] = (__bf16)v[r];
          l4[r] = (__bf16)(v[r] - (float)h4[r]);
        }
        const size_t b = (size_t)(row >> 10), rr = row & 1023;
        const size_t o = b * g.sCb + (size_t)col * g.ldc + rr;
        *(bf16x4*)&Chi[o] = h4;
        *(bf16x4*)&Clo[o] = l4;
      }
    }
}

} // namespace

extern "C" void kernel_launch(void* const* d_in, const int* in_sizes, int n_in,
                              void* d_out, int out_size, void* d_ws, size_t ws_size,
                              hipStream_t stream) {
  (void)in_sizes; (void)n_in; (void)out_size; (void)ws_size;

  const float* v_in = (const float*)d_in[0];
  const float* q_in = (const float*)d_in[1];
  const float* k_in = (const float*)d_in[2];
  const int*   mask = (const int*)d_in[3];
  const float* Gm   = (const float*)d_in[4];
  const float* wq = (const float*)d_in[5];  const float* bq = (const float*)d_in[6];
  const float* wk = (const float*)d_in[7];  const float* bk = (const float*)d_in[8];
  const float* wv = (const float*)d_in[9];  const float* bv = (const float*)d_in[10];
  const float* wo = (const float*)d_in[11]; const float* bo = (const float*)d_in[12];

  float* out = (float*)d_out;                       // [B,S,D]
  float* aw  = out + (size_t)NB * S * D;            // [B,H,S,S] scores -> softmax in place

  // Workspace arena (MiB offsets; ws is ~1 GiB per harness poison evidence):
  //  0-48   : q/k/v input hi+lo (8 MiB each tensor half)
  //  48-64  : wqT,wkT,wvT,woT hi/lo (2 MiB each)
  //  64-80  : Qp hi/lo
  //  80-96  : KpT hi/lo        ([B][D][S])
  //  96-112 : VpT hi/lo        ([B][D][S])
  //  112-114: G bf16 (exact, 0/1 values)
  //  114-130: Khat hi/lo       ([B][S][D])
  //  130-146: attn hi/lo       ([B][S][D])
  //  146-274: awh bf16-hi copy of attn weights ([B,H,S,S])
  char* ws = (char*)d_ws;
  auto BF = [&](size_t mb) { return (__bf16*)(ws + (mb << 20)); };

  const size_t BSD = (size_t)NB * S * D;

  // --- input prep (3 launches) ---
  split3_k<<<dim3(1024, 1, 3), 256, 0, stream>>>(q_in, k_in, v_in, BF(0), BSD / 4);
  split_k<<<1024, 256, 0, stream>>>(Gm, BF(112), nullptr, (size_t)S * S / 4);
  tsplit4_k<<<dim3(32, 32, 4), dim3(32, 8), 0, stream>>>(wq, wk, wv, wo, BF(48));

  // --- projections: [4096,1024] @ W + b, epilogue-fused hi/lo split ---
  GemmArgs pa{};
  pa.N = D; pa.K = D; pa.ZH = 1;
  pa.lda = D; pa.ldb = D; pa.ldc = D;
  // Q: plain split layout [B,S,D]
  pa.Ah = BF(0);  pa.Al = BF(8);  pa.Bh = BF(48); pa.Bl = BF(50);
  pa.Chi = BF(64); pa.Clo = BF(72); pa.bias = bq;
  gemm_k<128, 128, 2, 2, true, true, 3><<<dim3(8, 32, 1), 256, 0, stream>>>(pa);
  // K: transposed split [B][D][S]
  pa.Ah = BF(16); pa.Al = BF(24); pa.Bh = BF(52); pa.Bl = BF(54);
  pa.Chi = BF(80); pa.Clo = BF(88); pa.bias = bk;
  pa.ldc = S; pa.sCb = (long long)D * S;
  gemm_k<128, 128, 2, 2, true, true, 4><<<dim3(8, 32, 1), 256, 0, stream>>>(pa);
  // V: transposed split [B][D][S]
  pa.Ah = BF(32); pa.Al = BF(40); pa.Bh = BF(56); pa.Bl = BF(58);
  pa.Chi = BF(96); pa.Clo = BF(104); pa.bias = bv;
  gemm_k<128, 128, 2, 2, true, true, 4><<<dim3(8, 32, 1), 256, 0, stream>>>(pa);

  // --- Khat[b] = G @ Kp[b] (G symmetric, exact bf16; B = KpT hi/lo), split-store hi/lo ---
  GemmArgs ka{};
  ka.N = D; ka.K = S; ka.ZH = 1;
  ka.lda = S; ka.ldb = S; ka.ldc = D;
  ka.sBb = (long long)D * S; ka.sCb = (long long)S * D;
  ka.Ah = BF(112); ka.Bh = BF(80); ka.Bl = BF(88);
  ka.Chi = BF(114); ka.Clo = BF(122); ka.bias = nullptr;
  gemm_k<128, 128, 2, 2, false, true, 3><<<dim3(8, 8, NB), 256, 0, stream>>>(ka);

  // --- scores[b,h] = Qh . Khat_h^T / 8 - 1e5*mask  ->  aw (raw scores, f32) ---
  GemmArgs sa{};
  sa.N = S; sa.K = DP; sa.ZH = NH;
  sa.lda = D; sa.ldb = D; sa.ldc = S;
  sa.sAb = (long long)S * D; sa.sAh = DP;
  sa.sBb = (long long)S * D; sa.sBh = DP;
  sa.sCb = (long long)NH * S * S; sa.sCh = (long long)S * S;
  sa.sMb = (long long)S * S;
  sa.Ah = BF(64); sa.Al = BF(72); sa.Bh = BF(114); sa.Bl = BF(122);
  sa.C = aw; sa.mask = mask;
  gemm_k<128, 128, 2, 2, true, true, 2><<<dim3(8, 8, NB * NH), 256, 0, stream>>>(sa);

  // --- softmax rows in place (output #1) + bf16-hi copy for AV ---
  softmax_k<<<NB * NH * S, 256, 0, stream>>>(aw, BF(146));

  // --- attn[b,:,h*64:..] = AW[b,h] @ Vh (A = bf16-hi weights), split-store hi/lo ---
  GemmArgs va{};
  va.N = DP; va.K = S; va.ZH = NH;
  va.lda = S; va.ldb = S; va.ldc = D;
  va.sAb = (long long)NH * S * S; va.sAh = (long long)S * S;
  va.sBb = (long long)D * S;      va.sBh = (long long)DP * S;
  va.sCb = (long long)S * D;      va.sCh = DP;
  va.Ah = BF(146); va.Bh = BF(96); va.Bl = BF(104);
  va.Chi = BF(130); va.Clo = BF(138); va.bias = nullptr;
  gemm_k<128, 64, 2, 2, false, true, 3><<<dim3(1, 8, NB * NH), 256, 0, stream>>>(va);

  // --- output = attn @ wo + bo (f32 store) ---
  GemmArgs fa{};
  fa.N = D; fa.K = D; fa.ZH = 1;
  fa.lda = D; fa.ldb = D; fa.ldc = D;
  fa.Ah = BF(130); fa.Al = BF(138); fa.Bh = BF(60); fa.Bl = BF(62);
  fa.C = out; fa.bias = bo;
  gemm_k<128, 128, 2, 2, true, true, 0><<<dim3(8, 32, 1), 256, 0, stream>>>(fa);
}

// Round 3
// 772.159 us; speedup vs baseline: 1.1753x; 1.1211x over previous
//
#include <hip/hip_runtime.h>
#include <cstdint>
#include <cstddef>

#define AS1 __attribute__((address_space(1)))
#define AS3 __attribute__((address_space(3)))

typedef __bf16 bf16x8 __attribute__((ext_vector_type(8)));
typedef __bf16 bf16x4 __attribute__((ext_vector_type(4)));
typedef float  f32x4  __attribute__((ext_vector_type(4)));

namespace {

constexpr int NB = 4;      // batch
constexpr int S  = 1024;   // sequence length
constexpr int D  = 1024;   // model dim
constexpr int NH = 16;     // heads
constexpr int DP = 64;     // head dim

// ---------------- f32 -> bf16 hi (optionally +lo) split, float4-vectorized ----------------
__global__ void __launch_bounds__(256) split_k(const float* __restrict__ src,
                                               __bf16* __restrict__ hi,
                                               __bf16* __restrict__ lo,
                                               size_t n4) {
  size_t i = (size_t)blockIdx.x * blockDim.x + threadIdx.x;
  const size_t stride = (size_t)gridDim.x * blockDim.x;
  for (; i < n4; i += stride) {
    const float4 v = ((const float4*)src)[i];
    bf16x4 h;
    h[0] = (__bf16)v.x; h[1] = (__bf16)v.y; h[2] = (__bf16)v.z; h[3] = (__bf16)v.w;
    ((bf16x4*)hi)[i] = h;
    if (lo != nullptr) {
      bf16x4 l;
      l[0] = (__bf16)(v.x - (float)h[0]);
      l[1] = (__bf16)(v.y - (float)h[1]);
      l[2] = (__bf16)(v.z - (float)h[2]);
      l[3] = (__bf16)(v.w - (float)h[3]);
      ((bf16x4*)lo)[i] = l;
    }
  }
}

// ------------- batched q/k/v hi/lo split: z selects tensor; dst stride fixed -------------
__global__ void __launch_bounds__(256) split3_k(const float* __restrict__ s0,
                                                const float* __restrict__ s1,
                                                const float* __restrict__ s2,
                                                __bf16* __restrict__ hi0, size_t n4) {
  const float* srcs[3] = {s0, s1, s2};
  const float* src = srcs[blockIdx.z];
  __bf16* hi = hi0 + (size_t)blockIdx.z * 8388608;   // 16 MiB stride (hi+lo pair)
  __bf16* lo = hi + 4194304;                         // +8 MiB
  size_t i = (size_t)blockIdx.x * blockDim.x + threadIdx.x;
  const size_t stride = (size_t)gridDim.x * blockDim.x;
  for (; i < n4; i += stride) {
    const float4 v = ((const float4*)src)[i];
    bf16x4 h, l;
    h[0] = (__bf16)v.x; h[1] = (__bf16)v.y; h[2] = (__bf16)v.z; h[3] = (__bf16)v.w;
    l[0] = (__bf16)(v.x - (float)h[0]);
    l[1] = (__bf16)(v.y - (float)h[1]);
    l[2] = (__bf16)(v.z - (float)h[2]);
    l[3] = (__bf16)(v.w - (float)h[3]);
    ((bf16x4*)hi)[i] = h;
    ((bf16x4*)lo)[i] = l;
  }
}

// ------------- batched weight transpose+split: z selects {wq,wk,wv,wo}; 1024x1024 each -------------
__global__ void __launch_bounds__(256) tsplit4_k(const float* __restrict__ s0,
                                                 const float* __restrict__ s1,
                                                 const float* __restrict__ s2,
                                                 const float* __restrict__ s3,
                                                 __bf16* __restrict__ hi0) {
  __shared__ float tile[32][33];
  const float* srcs[4] = {s0, s1, s2, s3};
  const float* sp = srcs[blockIdx.z];
  __bf16* hp = hi0 + (size_t)blockIdx.z * 2097152;   // 4 MiB stride (hi+lo pair)
  __bf16* lp = hp + 1048576;                         // +2 MiB
  const int r0 = blockIdx.y * 32, c0 = blockIdx.x * 32;
  const int tx = threadIdx.x, ty = threadIdx.y;      // block (32,8)
  #pragma unroll
  for (int rr = ty; rr < 32; rr += 8)
    tile[rr][tx] = sp[(size_t)(r0 + rr) * D + c0 + tx];
  __syncthreads();
  #pragma unroll
  for (int cc = ty; cc < 32; cc += 8) {
    const float v = tile[tx][cc];                    // = src[r0+tx][c0+cc]
    const __bf16 h = (__bf16)v;
    const size_t o = (size_t)(c0 + cc) * D + r0 + tx;
    hp[o] = h;
    lp[o] = (__bf16)(v - (float)h);
  }
}

// ---------------- in-place row softmax + bf16-hi copy, rows of 1024 ----------------
__global__ void __launch_bounds__(256) softmax_k(float* __restrict__ aw,
                                                 __bf16* __restrict__ awh) {
  const size_t row = blockIdx.x;
  float* p = aw + row * 1024;
  const int tid = threadIdx.x;
  float4 v = ((const float4*)p)[tid];
  float m = fmaxf(fmaxf(v.x, v.y), fmaxf(v.z, v.w));
  #pragma unroll
  for (int off = 32; off > 0; off >>= 1) m = fmaxf(m, __shfl_xor(m, off));
  __shared__ float red[8];
  const int wv = tid >> 6, ln = tid & 63;
  if (ln == 0) red[wv] = m;
  __syncthreads();
  m = fmaxf(fmaxf(red[0], red[1]), fmaxf(red[2], red[3]));
  const float e0 = __expf(v.x - m), e1 = __expf(v.y - m);
  const float e2 = __expf(v.z - m), e3 = __expf(v.w - m);
  float s = (e0 + e1) + (e2 + e3);
  #pragma unroll
  for (int off = 32; off > 0; off >>= 1) s += __shfl_xor(s, off);
  if (ln == 0) red[4 + wv] = s;
  __syncthreads();
  s = (red[4] + red[5]) + (red[6] + red[7]);
  const float inv = 1.0f / s;
  float4 o; o.x = e0 * inv; o.y = e1 * inv; o.z = e2 * inv; o.w = e3 * inv;
  ((float4*)p)[tid] = o;
  bf16x4 hb;
  hb[0] = (__bf16)o.x; hb[1] = (__bf16)o.y; hb[2] = (__bf16)o.z; hb[3] = (__bf16)o.w;
  ((bf16x4*)(awh + row * 1024))[tid] = hb;
}

// ---------------- generic split-bf16 MFMA GEMM, 2-phase double-buffered ----------------
// C[m][n] = sum_k A[m][k] * Bt[n][k]   (Bt = B pre-transposed, bf16 hi/lo)
// Split passes: Ah*Bh (+ Ah*Bl if B_LO) (+ Al*Bh if A_LO).
// EPI: 0 = f32 store (+bias if non-null)
//      2 = scores: val/8 - 1e5*mask[row*N+col], f32 store
//      3 = split store: bf16 hi/lo, same layout (+bias if non-null)
//      4 = transposed split store per batch of 1024 rows: dst[zb*sCh + b*sCb + col*ldc + (row&1023)]
// z decomposition: z = zb*ZH + zh; strides sXb (per zb) and sXh (per zh).
// bias2: if non-null and zb==1, used instead of bias (for z-batched K/V projections).
struct GemmArgs {
  const __bf16 *Ah, *Al, *Bh, *Bl;
  float* C; __bf16* Chi; __bf16* Clo;
  const float* bias; const float* bias2; const int* mask;
  int N, K, ZH;
  long long lda, ldb, ldc;
  long long sAb, sAh, sBb, sBh, sCb, sCh, sMb;
};

template<int BM, int BN, int WM, int WN, bool A_LO, bool B_LO, int EPI>
__global__ void __launch_bounds__(WM * WN * 64) gemm_k(GemmArgs g) {
  constexpr int NW = WM * WN, NT = NW * 64, BK = 32;
  constexpr int WMsz = BM / WM, WNsz = BN / WN;
  constexpr int FM = WMsz / 16, FN = WNsz / 16;
  constexpr int ASZ = BM * BK, BSZ = BN * BK;
  static_assert((ASZ / 8) % NT == 0 && (BSZ / 8) % NT == 0, "stage divisibility");

  __shared__ __attribute__((aligned(16))) __bf16 Ash[2][ASZ];
  __shared__ __attribute__((aligned(16))) __bf16 Asl[2][A_LO ? ASZ : 8];
  __shared__ __attribute__((aligned(16))) __bf16 Bsh[2][BSZ];
  __shared__ __attribute__((aligned(16))) __bf16 Bsl[2][B_LO ? BSZ : 8];

  const int tid = threadIdx.x, wave = tid >> 6, lane = tid & 63;
  const int z = blockIdx.z;
  const int zb = z / g.ZH, zh = z - zb * g.ZH;

  const __bf16* Ah = g.Ah + (size_t)zb * g.sAb + (size_t)zh * g.sAh;
  const __bf16* Al = A_LO ? g.Al + (size_t)zb * g.sAb + (size_t)zh * g.sAh : nullptr;
  const __bf16* Bh = g.Bh + (size_t)zb * g.sBb + (size_t)zh * g.sBh;
  const __bf16* Bl = B_LO ? g.Bl + (size_t)zb * g.sBb + (size_t)zh * g.sBh : nullptr;
  float* C = (EPI == 0 || EPI == 2) ? g.C + (size_t)zb * g.sCb + (size_t)zh * g.sCh : nullptr;
  __bf16* Chi = g.Chi; __bf16* Clo = g.Clo;
  if constexpr (EPI == 3) {
    Chi += (size_t)zb * g.sCb + (size_t)zh * g.sCh;
    Clo += (size_t)zb * g.sCb + (size_t)zh * g.sCh;
  }
  if constexpr (EPI == 4) {
    Chi += (size_t)zb * g.sCh;          // tensor select (z-batched K/V)
    Clo += (size_t)zb * g.sCh;
  }
  const int* mk = (EPI == 2) ? g.mask + (size_t)zb * g.sMb : nullptr;
  const float* bias = (g.bias2 != nullptr && zb == 1) ? g.bias2 : g.bias;

  const int m0 = blockIdx.y * BM, n0 = blockIdx.x * BN;
  const int wm = wave / WN, wn = wave % WN;
  const int lc = lane & 15;            // A row / B col / C col within 16x16 frag
  const int lkb = (lane >> 4) * 8;     // k base for A/B fragments (contiguous 8)
  const int lr4 = (lane >> 4) * 4;     // C row group base

  // Per-thread staging coords (BK=32: 4 chunks of 8 bf16 per row)
  auto stage = [&](int buf, int k0) {
    constexpr int ITA = (ASZ / 8) / NT;
    #pragma unroll
    for (int i = 0; i < ITA; ++i) {
      const int cb = (i * NW + wave) * 64;            // wave-uniform chunk base
      const int ch = cb + lane;
      const int row = ch >> 2, c8 = ch & 3;
      const size_t go = (size_t)(m0 + row) * g.lda + k0 + c8 * 8;
      __builtin_amdgcn_global_load_lds((AS1 void*)(Ah + go),
                                       (AS3 void*)(&Ash[buf][cb * 8]), 16, 0, 0);
      if constexpr (A_LO)
        __builtin_amdgcn_global_load_lds((AS1 void*)(Al + go),
                                         (AS3 void*)(&Asl[buf][cb * 8]), 16, 0, 0);
    }
    constexpr int ITB = (BSZ / 8) / NT;
    #pragma unroll
    for (int i = 0; i < ITB; ++i) {
      const int cb = (i * NW + wave) * 64;
      const int ch = cb + lane;
      const int row = ch >> 2, c8 = ch & 3;
      const size_t go = (size_t)(n0 + row) * g.ldb + k0 + c8 * 8;
      __builtin_amdgcn_global_load_lds((AS1 void*)(Bh + go),
                                       (AS3 void*)(&Bsh[buf][cb * 8]), 16, 0, 0);
      if constexpr (B_LO)
        __builtin_amdgcn_global_load_lds((AS1 void*)(Bl + go),
                                         (AS3 void*)(&Bsl[buf][cb * 8]), 16, 0, 0);
    }
  };

  f32x4 acc[FM][FN] = {};

  stage(0, 0);
  __syncthreads();                     // compiler drains vmcnt before barrier
  int cur = 0;
  const int nk = g.K / BK;
  for (int t = 0; t < nk; ++t) {
    // ds-read current fragments first (no dependency on the staging below)
    bf16x8 ah[FM], al[FM], bh[FN], bl[FN];
    #pragma unroll
    for (int i = 0; i < FM; ++i) {
      const int r = wm * WMsz + i * 16 + lc;
      ah[i] = *(const bf16x8*)&Ash[cur][r * BK + lkb];
      if constexpr (A_LO) al[i] = *(const bf16x8*)&Asl[cur][r * BK + lkb];
    }
    #pragma unroll
    for (int j = 0; j < FN; ++j) {
      const int r = wn * WNsz + j * 16 + lc;
      bh[j] = *(const bf16x8*)&Bsh[cur][r * BK + lkb];
      if constexpr (B_LO) bl[j] = *(const bf16x8*)&Bsl[cur][r * BK + lkb];
    }
    // issue next-tile staging into the other buffer (overlaps with MFMA below)
    if (t + 1 < nk) stage(cur ^ 1, (t + 1) * BK);
    #pragma unroll
    for (int i = 0; i < FM; ++i)
      #pragma unroll
      for (int j = 0; j < FN; ++j) {
        acc[i][j] = __builtin_amdgcn_mfma_f32_16x16x32_bf16(ah[i], bh[j], acc[i][j], 0, 0, 0);
        if constexpr (B_LO)
          acc[i][j] = __builtin_amdgcn_mfma_f32_16x16x32_bf16(ah[i], bl[j], acc[i][j], 0, 0, 0);
        if constexpr (A_LO)
          acc[i][j] = __builtin_amdgcn_mfma_f32_16x16x32_bf16(al[i], bh[j], acc[i][j], 0, 0, 0);
      }
    __syncthreads();                   // one barrier per K-step: drains vmcnt (stage done)
    cur ^= 1;
  }

  // ---- epilogue: C/D frag mapping col=lane&15, row=(lane>>4)*4+r (m89-verified) ----
  #pragma unroll
  for (int i = 0; i < FM; ++i)
    #pragma unroll
    for (int j = 0; j < FN; ++j) {
      const int row = m0 + wm * WMsz + i * 16 + lr4;
      const int col = n0 + wn * WNsz + j * 16 + lc;
      float v[4];
      #pragma unroll
      for (int r = 0; r < 4; ++r) v[r] = acc[i][j][r];
      if constexpr (EPI != 2) {
        if (bias != nullptr) {
          const float b = bias[col];
          #pragma unroll
          for (int r = 0; r < 4; ++r) v[r] += b;
        }
      }
      if constexpr (EPI == 0) {
        #pragma unroll
        for (int r = 0; r < 4; ++r)
          C[(size_t)(row + r) * g.ldc + col] = v[r];
      }
      if constexpr (EPI == 2) {
        #pragma unroll
        for (int r = 0; r < 4; ++r)
          C[(size_t)(row + r) * g.ldc + col] =
              v[r] * 0.125f - 100000.0f * (float)mk[(size_t)(row + r) * g.N + col];
      }
      if constexpr (EPI == 3) {
        #pragma unroll
        for (int r = 0; r < 4; ++r) {
          const __bf16 h = (__bf16)v[r];
          const size_t o = (size_t)(row + r) * g.ldc + col;
          Chi[o] = h;
          Clo[o] = (__bf16)(v[r] - (float)h);
        }
      }
      if constexpr (EPI == 4) {
        bf16x4 h4, l4;
        #pragma unroll
        for (int r = 0; r < 4; ++r) {
          h4[r] = (__bf16)v[r];
          l4[r] = (__bf16)(v[r] - (float)h4[r]);
        }
        const size_t b = (size_t)(row >> 10), rr = row & 1023;
        const size_t o = b * g.sCb + (size_t)col * g.ldc + rr;
        *(bf16x4*)&Chi[o] = h4;
        *(bf16x4*)&Clo[o] = l4;
      }
    }
}

} // namespace

extern "C" void kernel_launch(void* const* d_in, const int* in_sizes, int n_in,
                              void* d_out, int out_size, void* d_ws, size_t ws_size,
                              hipStream_t stream) {
  (void)in_sizes; (void)n_in; (void)out_size; (void)ws_size;

  const float* v_in = (const float*)d_in[0];
  const float* q_in = (const float*)d_in[1];
  const float* k_in = (const float*)d_in[2];
  const int*   mask = (const int*)d_in[3];
  const float* Gm   = (const float*)d_in[4];
  const float* wq = (const float*)d_in[5];  const float* bq = (const float*)d_in[6];
  const float* wk = (const float*)d_in[7];  const float* bk = (const float*)d_in[8];
  const float* wv = (const float*)d_in[9];  const float* bv = (const float*)d_in[10];
  const float* wo = (const float*)d_in[11]; const float* bo = (const float*)d_in[12];

  float* out = (float*)d_out;                       // [B,S,D]
  float* aw  = out + (size_t)NB * S * D;            // [B,H,S,S] scores -> softmax in place

  // Workspace arena (MiB offsets):
  //  0-48   : q/k/v input hi+lo (8 MiB per half, 16 MiB per tensor)
  //  48-64  : wqT,wkT,wvT,woT hi/lo (2 MiB each half)
  //  64-80  : Qp hi/lo           ([B,S,D])
  //  80-96  : KpT hi/lo          ([B][D][S])
  //  96-112 : VpT hi/lo          ([B][D][S])
  //  112-114: G bf16 (exact, 0/1 values)
  //  114-130: Khat hi/lo         ([B,S,D])
  //  130-146: attn hi/lo         ([B,S,D])
  //  146-274: awh bf16-hi copy of attn weights ([B,H,S,S])
  char* ws = (char*)d_ws;
  auto BF = [&](size_t mb) { return (__bf16*)(ws + (mb << 20)); };

  const size_t BSD = (size_t)NB * S * D;

  // --- input prep (3 launches) ---
  split3_k<<<dim3(1024, 1, 3), 256, 0, stream>>>(q_in, k_in, v_in, BF(0), BSD / 4);
  split_k<<<1024, 256, 0, stream>>>(Gm, BF(112), nullptr, (size_t)S * S / 4);
  tsplit4_k<<<dim3(32, 32, 4), dim3(32, 8), 0, stream>>>(wq, wk, wv, wo, BF(48));

  // --- Q projection: BM=64 tile -> grid 512 (2 blocks/CU) ---
  GemmArgs pa{};
  pa.N = D; pa.K = D; pa.ZH = 1;
  pa.lda = D; pa.ldb = D; pa.ldc = D;
  pa.Ah = BF(0);  pa.Al = BF(8);  pa.Bh = BF(48); pa.Bl = BF(50);
  pa.Chi = BF(64); pa.Clo = BF(72); pa.bias = bq;
  gemm_k<64, 128, 2, 2, true, true, 3><<<dim3(8, 64, 1), 256, 0, stream>>>(pa);

  // --- K+V projections z-batched (z=zb selects tensor): grid 512, transposed split store ---
  GemmArgs kv{};
  kv.N = D; kv.K = D; kv.ZH = 1;
  kv.lda = D; kv.ldb = D; kv.ldc = S;
  kv.Ah = BF(16); kv.Al = BF(24); kv.sAb = 8388608;     // k -> v stride (elems)
  kv.Bh = BF(52); kv.Bl = BF(54); kv.sBb = 2097152;     // wkT -> wvT stride (elems)
  kv.Chi = BF(80); kv.Clo = BF(88);
  kv.sCh = 8388608;                                     // KpT -> VpT stride (elems)
  kv.sCb = (long long)D * S;                            // per-batch stride within tensor
  kv.bias = bk; kv.bias2 = bv;
  gemm_k<128, 128, 2, 2, true, true, 4><<<dim3(8, 32, 2), 256, 0, stream>>>(kv);

  // --- Khat[b] = G @ Kp[b] (G exact bf16; B = KpT hi/lo), BM=64 -> grid 512 ---
  GemmArgs ka{};
  ka.N = D; ka.K = S; ka.ZH = 1;
  ka.lda = S; ka.ldb = S; ka.ldc = D;
  ka.sAb = 0;                                           // same G for all batches
  ka.sBb = (long long)D * S; ka.sCb = (long long)S * D;
  ka.Ah = BF(112); ka.Bh = BF(80); ka.Bl = BF(88);
  ka.Chi = BF(114); ka.Clo = BF(122);
  gemm_k<64, 128, 2, 2, false, true, 3><<<dim3(8, 16, NB), 256, 0, stream>>>(ka);

  // --- scores[b,h] = Qh . Khat_h^T / 8 - 1e5*mask  ->  aw (raw scores, f32) ---
  GemmArgs sa{};
  sa.N = S; sa.K = DP; sa.ZH = NH;
  sa.lda = D; sa.ldb = D; sa.ldc = S;
  sa.sAb = (long long)S * D; sa.sAh = DP;
  sa.sBb = (long long)S * D; sa.sBh = DP;
  sa.sCb = (long long)NH * S * S; sa.sCh = (long long)S * S;
  sa.sMb = (long long)S * S;
  sa.Ah = BF(64); sa.Al = BF(72); sa.Bh = BF(114); sa.Bl = BF(122);
  sa.C = aw; sa.mask = mask;
  gemm_k<128, 128, 2, 2, true, true, 2><<<dim3(8, 8, NB * NH), 256, 0, stream>>>(sa);

  // --- softmax rows in place (output #1) + bf16-hi copy for AV ---
  softmax_k<<<NB * NH * S, 256, 0, stream>>>(aw, BF(146));

  // --- attn[b,:,h*64:..] = AW[b,h] @ Vh (A = bf16-hi weights), split-store hi/lo ---
  GemmArgs va{};
  va.N = DP; va.K = S; va.ZH = NH;
  va.lda = S; va.ldb = S; va.ldc = D;
  va.sAb = (long long)NH * S * S; va.sAh = (long long)S * S;
  va.sBb = (long long)D * S;      va.sBh = (long long)DP * S;
  va.sCb = (long long)S * D;      va.sCh = DP;
  va.Ah = BF(146); va.Bh = BF(96); va.Bl = BF(104);
  va.Chi = BF(130); va.Clo = BF(138);
  gemm_k<128, 64, 2, 2, false, true, 3><<<dim3(1, 8, NB * NH), 256, 0, stream>>>(va);

  // --- output = attn @ wo + bo (f32 store), BM=64 -> grid 512 ---
  GemmArgs fa{};
  fa.N = D; fa.K = D; fa.ZH = 1;
  fa.lda = D; fa.ldb = D; fa.ldc = D;
  fa.Ah = BF(130); fa.Al = BF(138); fa.Bh = BF(60); fa.Bl = BF(62);
  fa.C = out; fa.bias = bo;
  gemm_k<64, 128, 2, 2, true, true, 0><<<dim3(8, 64, 1), 256, 0, stream>>>(fa);
}